// Round 6
// baseline (303.035 us; speedup 1.0000x reference)
//
#include <hip/hip_runtime.h>
#include <hip/hip_bf16.h>
#include <math.h>

#define S_LEN 2048
#define DIN   2048
#define NH    32
#define NKV   8
#define HD    64
#define DOUT  2048        // NH*HD
#define QKVN  3072        // DOUT + 2*KVD
#define KOFF  2048        // k col offset in qkv
#define VOFF  2560        // v col offset in qkv

typedef __attribute__((ext_vector_type(8))) short short8v;    // 8 bf16 (4 VGPRs)
typedef __attribute__((ext_vector_type(8))) unsigned short ushort8v;
typedef __attribute__((ext_vector_type(4))) float float4v;

__device__ __forceinline__ float bf2f(unsigned short u) {
    union { float f; unsigned u; } c; c.u = ((unsigned)u) << 16; return c.f;
}
__device__ __forceinline__ unsigned short f2bf(float f) {
    union { float f; unsigned u; } c; c.f = f;
    unsigned r = c.u + 0x7fffu + ((c.u >> 16) & 1u);   // RNE
    return (unsigned short)(r >> 16);
}

// ---------------------------------------------------------------------------
// Fused preprocessing, ONE launch, grid sections:
//   [0, 6144)        : Wq|Wk|Wv fp32 [K][N] -> bf16 [N][K] into W1 (32x32 tiles)
//   [6144, 10240)    : Wo transpose into WoT
//   [10240, 14336)   : x fp32 -> bf16 cast into XB
// ---------------------------------------------------------------------------
__global__ __launch_bounds__(256) void prep(const float* __restrict__ Wq,
                                            const float* __restrict__ Wk,
                                            const float* __restrict__ Wv,
                                            const float* __restrict__ Wo,
                                            const float* __restrict__ x,
                                            unsigned short* __restrict__ W1,
                                            unsigned short* __restrict__ WoT,
                                            unsigned short* __restrict__ XB) {
    __shared__ float t[32][33];
    const int a = blockIdx.x;
    const int tx = threadIdx.x & 31, ty = threadIdx.x >> 5;
    if (a < 6144) {                       // qkv weights: grid (96, 64)
        const int n0 = (a % 96) * 32, k0 = (a / 96) * 32;
        const float* src; int nn0, Nsrc;
        if (n0 < KOFF)      { src = Wq; nn0 = n0;        Nsrc = DOUT; }
        else if (n0 < VOFF) { src = Wk; nn0 = n0 - KOFF; Nsrc = 512; }
        else                { src = Wv; nn0 = n0 - VOFF; Nsrc = 512; }
#pragma unroll
        for (int j = ty; j < 32; j += 8)
            t[j][tx] = src[(size_t)(k0 + j) * Nsrc + nn0 + tx];
        __syncthreads();
#pragma unroll
        for (int j = ty; j < 32; j += 8)
            W1[(size_t)(n0 + j) * DIN + k0 + tx] = f2bf(t[tx][j]);
    } else if (a < 10240) {               // Wo: grid (64, 64), K=DOUT rows, N=DIN
        const int b = a - 6144;
        const int n0 = (b % 64) * 32, k0 = (b / 64) * 32;
#pragma unroll
        for (int j = ty; j < 32; j += 8)
            t[j][tx] = Wo[(size_t)(k0 + j) * DIN + n0 + tx];
        __syncthreads();
#pragma unroll
        for (int j = ty; j < 32; j += 8)
            WoT[(size_t)(n0 + j) * DOUT + k0 + tx] = f2bf(t[tx][j]);
    } else {                              // x cast: 4096 blocks x 1024 elems
        const int i = (a - 10240) * 1024 + threadIdx.x * 4;
        float4 v = *(const float4*)(x + i);
        XB[i + 0] = f2bf(v.x); XB[i + 1] = f2bf(v.y);
        XB[i + 2] = f2bf(v.z); XB[i + 3] = f2bf(v.w);
    }
}

// ---------------------------------------------------------------------------
// bf16 MFMA GEMM, 128x64 tile, BK=32, 4 waves stacked in M (wave = 32x64).
// FUSE=1: bf16 out + per-head RMSNorm+RoPE epilogue (block col = one head).
// FUSE=0: fp32 out, plain.
// ---------------------------------------------------------------------------
template <int FUSE>
__global__ __launch_bounds__(256) void gemm64(const unsigned short* __restrict__ A,
                                              const unsigned short* __restrict__ Bt,
                                              void* __restrict__ Cv, int M, int N, int K,
                                              const float* __restrict__ qnw,
                                              const float* __restrict__ knw,
                                              const float* __restrict__ cosb,
                                              const float* __restrict__ sinb) {
    __shared__ __attribute__((aligned(16))) unsigned short As[128 * 32];
    __shared__ __attribute__((aligned(16))) unsigned short Bs[64 * 32];
    const int tid = threadIdx.x, lane = tid & 63, w = tid >> 6;
    const int bm = blockIdx.y * 128, bn = blockIdx.x * 64;
    const int wm = w * 32;

    float4v acc[2][4];
#pragma unroll
    for (int i = 0; i < 2; i++)
#pragma unroll
        for (int j = 0; j < 4; j++) acc[i][j] = (float4v){0.f, 0.f, 0.f, 0.f};

    const int lr = lane >> 2, lc = (lane & 3) * 8;
    const unsigned short* Ag0 = A + (size_t)(bm + w * 32 + lr) * K + lc;
    const unsigned short* Ag1 = Ag0 + (size_t)16 * K;
    const unsigned short* Bg  = Bt + (size_t)(bn + w * 16 + lr) * K + lc;
    unsigned short* Al0 = As + (w * 32) * 32;
    unsigned short* Al1 = As + (w * 32 + 16) * 32;
    unsigned short* Bl  = Bs + (w * 16) * 32;

    const int frow = lane & 15, fk = (lane >> 4) * 8;

    for (int k0 = 0; k0 < K; k0 += 32) {
        __syncthreads();
        __builtin_amdgcn_global_load_lds(
            (const __attribute__((address_space(1))) void*)(Ag0 + k0),
            (__attribute__((address_space(3))) void*)Al0, 16, 0, 0);
        __builtin_amdgcn_global_load_lds(
            (const __attribute__((address_space(1))) void*)(Ag1 + k0),
            (__attribute__((address_space(3))) void*)Al1, 16, 0, 0);
        __builtin_amdgcn_global_load_lds(
            (const __attribute__((address_space(1))) void*)(Bg + k0),
            (__attribute__((address_space(3))) void*)Bl, 16, 0, 0);
        __syncthreads();

        short8v af[2], bf[4];
#pragma unroll
        for (int fm = 0; fm < 2; fm++)
            af[fm] = *(const short8v*)(As + (wm + fm * 16 + frow) * 32 + fk);
#pragma unroll
        for (int fn = 0; fn < 4; fn++)
            bf[fn] = *(const short8v*)(Bs + (fn * 16 + frow) * 32 + fk);
#pragma unroll
        for (int fm = 0; fm < 2; fm++)
#pragma unroll
            for (int fn = 0; fn < 4; fn++)
                acc[fm][fn] = __builtin_amdgcn_mfma_f32_16x16x32_bf16(
                    af[fm], bf[fn], acc[fm][fn], 0, 0, 0);
    }

    const int quad = lane >> 4, col16 = lane & 15;
    if constexpr (FUSE == 1) {
        unsigned short* C = (unsigned short*)Cv;
        const int head = bn >> 6;                 // one head per block col
        if (head < 40) {
            const float* nw = (head < 32) ? qnw : knw;
            float wv[4];
#pragma unroll
            for (int fn = 0; fn < 4; fn++) wv[fn] = nw[fn * 16 + col16];
#pragma unroll
            for (int fm = 0; fm < 2; fm++)
#pragma unroll
                for (int r = 0; r < 4; r++) {
                    float x0 = acc[fm][0][r], x1 = acc[fm][1][r];
                    float x2 = acc[fm][2][r], x3 = acc[fm][3][r];
                    float ss = x0 * x0 + x1 * x1 + x2 * x2 + x3 * x3;
                    ss += __shfl_xor(ss, 1); ss += __shfl_xor(ss, 2);
                    ss += __shfl_xor(ss, 4); ss += __shfl_xor(ss, 8);
                    const float inv = rsqrtf(ss * (1.0f / 64.0f) + 1e-6f);
                    float xn[4] = {x0 * inv * wv[0], x1 * inv * wv[1],
                                   x2 * inv * wv[2], x3 * inv * wv[3]};
                    const int row = bm + wm + fm * 16 + quad * 4 + r;
                    const float* cr = cosb + (size_t)row * HD;
                    const float* sr = sinb + (size_t)row * HD;
#pragma unroll
                    for (int fn = 0; fn < 4; fn++) {
                        const float rot = (fn < 2) ? -xn[fn + 2] : xn[fn - 2];
                        const float res = xn[fn] * cr[fn * 16 + col16] +
                                          rot * sr[fn * 16 + col16];
                        C[(size_t)row * N + bn + fn * 16 + col16] = f2bf(res);
                    }
                }
        } else {
#pragma unroll
            for (int fm = 0; fm < 2; fm++)
#pragma unroll
                for (int fn = 0; fn < 4; fn++)
#pragma unroll
                    for (int r = 0; r < 4; r++)
                        C[(size_t)(bm + wm + fm * 16 + quad * 4 + r) * N +
                          bn + fn * 16 + col16] = f2bf(acc[fm][fn][r]);
        }
    } else {
        float* C = (float*)Cv;
#pragma unroll
        for (int fm = 0; fm < 2; fm++)
#pragma unroll
            for (int fn = 0; fn < 4; fn++)
#pragma unroll
                for (int r = 0; r < 4; r++)
                    C[(size_t)(bm + wm + fm * 16 + quad * 4 + r) * N +
                      bn + fn * 16 + col16] = acc[fm][fn][r];
    }
}

// ---------------------------------------------------------------------------
// MFMA flash attention v3 (causal, GQA), fixed-max softmax.
// Block = (kv head g) x (16-query tile); 4 waves = 4 q-heads of the group.
// 1024 blocks, all co-resident at 4/CU (LDS 27.6KB, VGPR<=128).
// K B-frags DIRECT from global (L2), prefetched one tile ahead.
// V staged to LDS transposed, double-buffered, reg-prefetched -> 1 barrier/iter.
// P round-trip in per-wave LDS tile (no barrier; same-wave lgkmcnt ordering).
// Work-balanced tile map: CU-group {b,b+32,b+64,b+96} -> tiles {b,63-b,64+b,127-b}.
// ---------------------------------------------------------------------------
#define PSTR 72   // LDS row stride (shorts): 144B, 16B-aligned

__global__ __launch_bounds__(256, 4) void flash_mfma(const unsigned short* __restrict__ qb,
                                                     const unsigned short* __restrict__ kb,
                                                     const unsigned short* __restrict__ vb,
                                                     unsigned short* __restrict__ ob) {
    __shared__ __attribute__((aligned(16))) unsigned short Vt[2][64 * PSTR];
    __shared__ __attribute__((aligned(16))) unsigned short Ps[64 * PSTR];

    const int tid = threadIdx.x, lane = tid & 63, w = tid >> 6;
    const int col = lane & 15, quad = lane >> 4;
    const int bid = blockIdx.x;
    const int g = bid & 7;                    // kv head
    const int bx = bid >> 3;                  // 0..127
    const int kk = bx >> 5, bb = bx & 31;     // balanced tile map
    const int tile = (kk == 0) ? bb : (kk == 1) ? 63 - bb : (kk == 2) ? 64 + bb : 127 - bb;
    const int s0 = tile * 16;
    const int h = g * 4 + w;

    const float C1 = 0.18033688011112042f;    // 0.125 * log2(e)
    const float C2 = 12.262908856239697f;     // 8.5  * log2(e)

    // Q fragments (A-layout), loaded once: rows s0+col
    short8v qf[2];
#pragma unroll
    for (int ks = 0; ks < 2; ks++)
        qf[ks] = *(const short8v*)(qb + (size_t)(s0 + col) * QKVN +
                                   h * HD + ks * 32 + quad * 8);

    float4v O[4];
    float lsum[4];
#pragma unroll
    for (int df = 0; df < 4; df++) O[df] = (float4v){0.f, 0.f, 0.f, 0.f};
#pragma unroll
    for (int r = 0; r < 4; r++) lsum[r] = 0.f;

    // V staging: thread -> key = tid&63, dim block = tid>>6 (16 dims)
    const int vkey = tid & 63, vdb = tid >> 6;
    const unsigned short* vg = vb + (size_t)vkey * QKVN + g * HD + vdb * 16;
    ushort8v va0 = *(const ushort8v*)vg;
    ushort8v va1 = *(const ushort8v*)(vg + 8);

    // K B-frag base (direct global): row = t0 + nf*16 + col
    const unsigned short* kgb = kb + (size_t)col * QKVN + g * HD + quad * 8;

    // preload kf for tile 0
    short8v kf[4][2];
#pragma unroll
    for (int nf = 0; nf < 4; nf++)
#pragma unroll
        for (int ks = 0; ks < 2; ks++)
            kf[nf][ks] = *(const short8v*)(kgb + (size_t)(nf * 16) * QKVN + ks * 32);

    const int nt = (s0 + 79) >> 6;
    for (int it = 0; it < nt; it++) {
        const int c = it & 1;
        const int t0 = it * 64;
        // commit V regs to LDS buffer c (transposed [dim][key])
        {
            unsigned short* vd = Vt[c] + (size_t)(vdb * 16) * PSTR + vkey;
#pragma unroll
            for (int j = 0; j < 8; j++) vd[j * PSTR] = va0[j];
#pragma unroll
            for (int j = 0; j < 8; j++) vd[(8 + j) * PSTR] = va1[j];
        }
        __syncthreads();
        // prefetch next V tile into regs
        if (it + 1 < nt) {
            const size_t off = (size_t)(it + 1) * 64 * QKVN;
            va0 = *(const ushort8v*)(vg + off);
            va1 = *(const ushort8v*)(vg + off + 8);
        }

        const bool edge = (t0 + 63 > s0);

        // QK^T
        float4v sc[4];
#pragma unroll
        for (int nf = 0; nf < 4; nf++) {
            sc[nf] = (float4v){0.f, 0.f, 0.f, 0.f};
#pragma unroll
            for (int ks = 0; ks < 2; ks++)
                sc[nf] = __builtin_amdgcn_mfma_f32_16x16x32_bf16(qf[ks], kf[nf][ks],
                                                                 sc[nf], 0, 0, 0);
        }
        // prefetch kf for next tile (hidden under softmax + PV + barrier)
        if (it + 1 < nt) {
            const size_t off = (size_t)(t0 + 64) * QKVN;
#pragma unroll
            for (int nf = 0; nf < 4; nf++)
#pragma unroll
                for (int ks = 0; ks < 2; ks++)
                    kf[nf][ks] = *(const short8v*)(kgb + off + (size_t)(nf * 16) * QKVN +
                                                   ks * 32);
        }

        // fixed-max softmax: p = exp2(score*C1 - C2), no reductions in loop
#pragma unroll
        for (int nf = 0; nf < 4; nf++)
#pragma unroll
            for (int r = 0; r < 4; r++) {
                float arg = sc[nf][r] * C1 - C2;
                if (edge) {
                    const int qg = s0 + quad * 4 + r;
                    const int kg_ = t0 + nf * 16 + col;
                    arg = (kg_ <= qg) ? arg : -100.f;
                }
                const float p = exp2f(arg);
                sc[nf][r] = p;
                lsum[r] += p;
            }
        // write P (bf16) to per-wave LDS tile, XOR-swizzled col-blocks
        {
            unsigned short* pw = Ps + (size_t)(w * 16 + quad * 4) * PSTR;
#pragma unroll
            for (int nf = 0; nf < 4; nf++) {
                const int pb = (nf ^ quad) * 16;
#pragma unroll
                for (int r = 0; r < 4; r++)
                    pw[r * PSTR + pb + col] = f2bf(sc[nf][r]);
            }
        }

        // PV: vf B-frags from Vt, pf A-frags from Ps (same-wave, no barrier)
        short8v vf[4][2];
#pragma unroll
        for (int df = 0; df < 4; df++)
#pragma unroll
            for (int ks = 0; ks < 2; ks++)
                vf[df][ks] = *(const short8v*)(Vt[c] + (df * 16 + col) * PSTR +
                                               ks * 32 + quad * 8);
#pragma unroll
        for (int ks = 0; ks < 2; ks++) {
            const int lb = ks * 2 + (quad >> 1);
            short8v pf = *(const short8v*)(Ps + (size_t)(w * 16 + col) * PSTR +
                                           ((lb ^ (col >> 2)) * 16 + (quad & 1) * 8));
#pragma unroll
            for (int df = 0; df < 4; df++)
                O[df] = __builtin_amdgcn_mfma_f32_16x16x32_bf16(pf, vf[df][ks],
                                                                O[df], 0, 0, 0);
        }
    }

    // epilogue: reduce l across 16 cols of each row, divide, store
#pragma unroll
    for (int r = 0; r < 4; r++) {
        float l = lsum[r];
        l += __shfl_xor(l, 1); l += __shfl_xor(l, 2);
        l += __shfl_xor(l, 4); l += __shfl_xor(l, 8);
        lsum[r] = 1.0f / l;
    }
#pragma unroll
    for (int df = 0; df < 4; df++)
#pragma unroll
        for (int r = 0; r < 4; r++) {
            float v = O[df][r] * lsum[r];
            ob[(size_t)(s0 + quad * 4 + r) * DOUT + h * HD + df * 16 + col] = f2bf(v);
        }
}

// ---------------------------------------------------------------------------
extern "C" void kernel_launch(void* const* d_in, const int* in_sizes, int n_in,
                              void* d_out, int out_size, void* d_ws, size_t ws_size,
                              hipStream_t stream) {
    const float* x    = (const float*)d_in[0];
    const float* cosb = (const float*)d_in[2];
    const float* sinb = (const float*)d_in[3];
    const float* Wq   = (const float*)d_in[4];
    const float* Wk   = (const float*)d_in[5];
    const float* Wv   = (const float*)d_in[6];
    const float* Wo   = (const float*)d_in[7];
    const float* qw   = (const float*)d_in[8];
    const float* kw   = (const float*)d_in[9];
    float* out = (float*)d_out;

    // ws layout (40 MB total):
    unsigned short* W1  = (unsigned short*)d_ws;                       // 3072x2048 bf16 (12.6MB)
    unsigned short* WoT = W1 + (size_t)QKVN * DIN;                     // 2048x2048 bf16 (8.4MB)
    unsigned short* XB  = WoT + (size_t)DIN * DOUT;                    // 2048x2048 bf16 (x, then ctx)
    unsigned short* QKV = XB + (size_t)S_LEN * DIN;                    // 2048x3072 bf16 (12.6MB)

    dim3 blk256(256);

    prep<<<dim3(14336), blk256, 0, stream>>>(Wq, Wk, Wv, Wo, x, W1, WoT, XB);

    gemm64<1><<<dim3(QKVN / 64, S_LEN / 128), blk256, 0, stream>>>(
        XB, W1, QKV, S_LEN, QKVN, DIN, qw, kw, cosb, sinb);

    flash_mfma<<<dim3((S_LEN / 16) * NKV), blk256, 0, stream>>>(
        QKV, QKV + KOFF, QKV + VOFF, XB);

    gemm64<0><<<dim3(DIN / 64, S_LEN / 128), blk256, 0, stream>>>(
        XB, WoT, out, S_LEN, DIN, DOUT, nullptr, nullptr, nullptr, nullptr);
}

// Round 7
// 282.505 us; speedup vs baseline: 1.0727x; 1.0727x over previous
//
#include <hip/hip_runtime.h>
#include <hip/hip_bf16.h>
#include <math.h>

#define S_LEN 2048
#define DIN   2048
#define NH    32
#define NKV   8
#define HD    64
#define DOUT  2048        // NH*HD
#define QKVN  3072        // DOUT + 2*KVD
#define KOFF  2048        // k col offset in qkv
#define VOFF  2560        // v col offset in qkv

typedef __attribute__((ext_vector_type(8))) short short8v;    // 8 bf16 (4 VGPRs)
typedef __attribute__((ext_vector_type(8))) unsigned short ushort8v;
typedef __attribute__((ext_vector_type(4))) unsigned short ushort4v;
typedef __attribute__((ext_vector_type(4))) float float4v;

__device__ __forceinline__ float bf2f(unsigned short u) {
    union { float f; unsigned u; } c; c.u = ((unsigned)u) << 16; return c.f;
}
__device__ __forceinline__ unsigned short f2bf(float f) {
    union { float f; unsigned u; } c; c.f = f;
    unsigned r = c.u + 0x7fffu + ((c.u >> 16) & 1u);   // RNE
    return (unsigned short)(r >> 16);
}
__device__ __forceinline__ unsigned short f2h(float f) {
    union { _Float16 h; unsigned short u; } c; c.h = (_Float16)f; return c.u;
}
__device__ __forceinline__ float h2f(unsigned short u) {
    union { _Float16 h; unsigned short u; } c; c.u = u; return (float)c.h;
}

// ---------------------------------------------------------------------------
// Fused preprocessing, ONE launch, grid sections:
//   [0, 6144)        : Wq|Wk|Wv fp32 [K][N] -> bf16 [N][K] into W1 (32x32 tiles)
//   [6144, 10240)    : Wo transpose into WoT
//   [10240, 14336)   : x fp32 -> bf16 cast into XB
// ---------------------------------------------------------------------------
__global__ __launch_bounds__(256) void prep(const float* __restrict__ Wq,
                                            const float* __restrict__ Wk,
                                            const float* __restrict__ Wv,
                                            const float* __restrict__ Wo,
                                            const float* __restrict__ x,
                                            unsigned short* __restrict__ W1,
                                            unsigned short* __restrict__ WoT,
                                            unsigned short* __restrict__ XB) {
    __shared__ float t[32][33];
    const int a = blockIdx.x;
    const int tx = threadIdx.x & 31, ty = threadIdx.x >> 5;
    if (a < 6144) {                       // qkv weights: grid (96, 64)
        const int n0 = (a % 96) * 32, k0 = (a / 96) * 32;
        const float* src; int nn0, Nsrc;
        if (n0 < KOFF)      { src = Wq; nn0 = n0;        Nsrc = DOUT; }
        else if (n0 < VOFF) { src = Wk; nn0 = n0 - KOFF; Nsrc = 512; }
        else                { src = Wv; nn0 = n0 - VOFF; Nsrc = 512; }
#pragma unroll
        for (int j = ty; j < 32; j += 8)
            t[j][tx] = src[(size_t)(k0 + j) * Nsrc + nn0 + tx];
        __syncthreads();
#pragma unroll
        for (int j = ty; j < 32; j += 8)
            W1[(size_t)(n0 + j) * DIN + k0 + tx] = f2bf(t[tx][j]);
    } else if (a < 10240) {               // Wo: grid (64, 64), K=DOUT rows, N=DIN
        const int b = a - 6144;
        const int n0 = (b % 64) * 32, k0 = (b / 64) * 32;
#pragma unroll
        for (int j = ty; j < 32; j += 8)
            t[j][tx] = Wo[(size_t)(k0 + j) * DIN + n0 + tx];
        __syncthreads();
#pragma unroll
        for (int j = ty; j < 32; j += 8)
            WoT[(size_t)(n0 + j) * DOUT + k0 + tx] = f2bf(t[tx][j]);
    } else {                              // x cast: 4096 blocks x 1024 elems
        const int i = (a - 10240) * 1024 + threadIdx.x * 4;
        float4 v = *(const float4*)(x + i);
        XB[i + 0] = f2bf(v.x); XB[i + 1] = f2bf(v.y);
        XB[i + 2] = f2bf(v.z); XB[i + 3] = f2bf(v.w);
    }
}

// ---------------------------------------------------------------------------
// bf16 MFMA GEMM, 128x64 tile, BK=32, 4 waves stacked in M (wave = 32x64).
// FUSE=1: bf16 out + per-head RMSNorm+RoPE epilogue (block col = one head).
// FUSE=0: fp32 out, plain.
// ---------------------------------------------------------------------------
template <int FUSE>
__global__ __launch_bounds__(256) void gemm64(const unsigned short* __restrict__ A,
                                              const unsigned short* __restrict__ Bt,
                                              void* __restrict__ Cv, int M, int N, int K,
                                              const float* __restrict__ qnw,
                                              const float* __restrict__ knw,
                                              const float* __restrict__ cosb,
                                              const float* __restrict__ sinb) {
    __shared__ __attribute__((aligned(16))) unsigned short As[128 * 32];
    __shared__ __attribute__((aligned(16))) unsigned short Bs[64 * 32];
    const int tid = threadIdx.x, lane = tid & 63, w = tid >> 6;
    const int bm = blockIdx.y * 128, bn = blockIdx.x * 64;
    const int wm = w * 32;

    float4v acc[2][4];
#pragma unroll
    for (int i = 0; i < 2; i++)
#pragma unroll
        for (int j = 0; j < 4; j++) acc[i][j] = (float4v){0.f, 0.f, 0.f, 0.f};

    const int lr = lane >> 2, lc = (lane & 3) * 8;
    const unsigned short* Ag0 = A + (size_t)(bm + w * 32 + lr) * K + lc;
    const unsigned short* Ag1 = Ag0 + (size_t)16 * K;
    const unsigned short* Bg  = Bt + (size_t)(bn + w * 16 + lr) * K + lc;
    unsigned short* Al0 = As + (w * 32) * 32;
    unsigned short* Al1 = As + (w * 32 + 16) * 32;
    unsigned short* Bl  = Bs + (w * 16) * 32;

    const int frow = lane & 15, fk = (lane >> 4) * 8;

    for (int k0 = 0; k0 < K; k0 += 32) {
        __syncthreads();
        __builtin_amdgcn_global_load_lds(
            (const __attribute__((address_space(1))) void*)(Ag0 + k0),
            (__attribute__((address_space(3))) void*)Al0, 16, 0, 0);
        __builtin_amdgcn_global_load_lds(
            (const __attribute__((address_space(1))) void*)(Ag1 + k0),
            (__attribute__((address_space(3))) void*)Al1, 16, 0, 0);
        __builtin_amdgcn_global_load_lds(
            (const __attribute__((address_space(1))) void*)(Bg + k0),
            (__attribute__((address_space(3))) void*)Bl, 16, 0, 0);
        __syncthreads();

        short8v af[2], bf[4];
#pragma unroll
        for (int fm = 0; fm < 2; fm++)
            af[fm] = *(const short8v*)(As + (wm + fm * 16 + frow) * 32 + fk);
#pragma unroll
        for (int fn = 0; fn < 4; fn++)
            bf[fn] = *(const short8v*)(Bs + (fn * 16 + frow) * 32 + fk);
#pragma unroll
        for (int fm = 0; fm < 2; fm++)
#pragma unroll
            for (int fn = 0; fn < 4; fn++)
                acc[fm][fn] = __builtin_amdgcn_mfma_f32_16x16x32_bf16(
                    af[fm], bf[fn], acc[fm][fn], 0, 0, 0);
    }

    const int quad = lane >> 4, col16 = lane & 15;
    if constexpr (FUSE == 1) {
        unsigned short* C = (unsigned short*)Cv;
        const int head = bn >> 6;                 // one head per block col
        if (head < 40) {
            const float* nw = (head < 32) ? qnw : knw;
            float wv[4];
#pragma unroll
            for (int fn = 0; fn < 4; fn++) wv[fn] = nw[fn * 16 + col16];
#pragma unroll
            for (int fm = 0; fm < 2; fm++)
#pragma unroll
                for (int r = 0; r < 4; r++) {
                    float x0 = acc[fm][0][r], x1 = acc[fm][1][r];
                    float x2 = acc[fm][2][r], x3 = acc[fm][3][r];
                    float ss = x0 * x0 + x1 * x1 + x2 * x2 + x3 * x3;
                    ss += __shfl_xor(ss, 1); ss += __shfl_xor(ss, 2);
                    ss += __shfl_xor(ss, 4); ss += __shfl_xor(ss, 8);
                    const float inv = rsqrtf(ss * (1.0f / 64.0f) + 1e-6f);
                    float xn[4] = {x0 * inv * wv[0], x1 * inv * wv[1],
                                   x2 * inv * wv[2], x3 * inv * wv[3]};
                    const int row = bm + wm + fm * 16 + quad * 4 + r;
                    const float* cr = cosb + (size_t)row * HD;
                    const float* sr = sinb + (size_t)row * HD;
#pragma unroll
                    for (int fn = 0; fn < 4; fn++) {
                        const float rot = (fn < 2) ? -xn[fn + 2] : xn[fn - 2];
                        const float res = xn[fn] * cr[fn * 16 + col16] +
                                          rot * sr[fn * 16 + col16];
                        C[(size_t)row * N + bn + fn * 16 + col16] = f2bf(res);
                    }
                }
        } else {
#pragma unroll
            for (int fm = 0; fm < 2; fm++)
#pragma unroll
                for (int fn = 0; fn < 4; fn++)
#pragma unroll
                    for (int r = 0; r < 4; r++)
                        C[(size_t)(bm + wm + fm * 16 + quad * 4 + r) * N +
                          bn + fn * 16 + col16] = f2bf(acc[fm][fn][r]);
        }
    } else {
        float* C = (float*)Cv;
#pragma unroll
        for (int fm = 0; fm < 2; fm++)
#pragma unroll
            for (int fn = 0; fn < 4; fn++)
#pragma unroll
                for (int r = 0; r < 4; r++)
                    C[(size_t)(bm + wm + fm * 16 + quad * 4 + r) * N +
                      bn + fn * 16 + col16] = acc[fm][fn][r];
    }
}

// ---------------------------------------------------------------------------
// MFMA flash attention v4 (causal, GQA), fixed-max softmax, KEY-SPLIT.
// Fixed-max softmax is additive across key ranges: two blocks per (g, qtile)
// each process half the 64-key tiles, writing partial O (fp16) and partial
// sum-of-p (fp32); combine() merges. 1024 blocks, ALL co-resident at 4/CU
// (LDS = 40960 B exactly), 16 waves/CU.
// Block: 32 q-rows x 4 heads (wave w = head g*4+w). Single-buffered K/V LDS
// with reg-prefetch (~100 VGPR; NO min-waves bound -- R6 showed a 64-VGPR cap
// makes the scheduler sink the prefetch loads, serializing on global latency).
// ---------------------------------------------------------------------------
#define KSTR 88    // K/V LDS row stride (shorts)
#define PPSTR 72   // P LDS row stride (shorts), 144B = 16B-aligned

__global__ __launch_bounds__(256) void flash_part(const unsigned short* __restrict__ qb,
                                                  const unsigned short* __restrict__ kb,
                                                  const unsigned short* __restrict__ vb,
                                                  unsigned short* __restrict__ Op,
                                                  float* __restrict__ Lp) {
    __shared__ __attribute__((aligned(16))) unsigned short Ks[64 * KSTR];
    __shared__ __attribute__((aligned(16))) unsigned short Vt[64 * KSTR];
    __shared__ __attribute__((aligned(16))) unsigned short Ps[128 * PPSTR];

    const int tid = threadIdx.x, lane = tid & 63, w = tid >> 6;
    const int col = lane & 15, quad = lane >> 4;
    const int bid = blockIdx.x;
    const int g = bid & 7;                    // kv head
    const int qtile = (bid >> 3) & 63;
    const int half = bid >> 9;                // 0 or 1
    const int s0 = qtile * 32;
    const int h = g * 4 + w;

    const int nt = (s0 + 95) >> 6;            // total 64-key tiles for this qtile
    const int nt0 = (nt + 1) >> 1;
    const int it_lo = half ? nt0 : 0;
    const int it_hi = half ? nt : nt0;

    const float C1 = 0.18033688011112042f;    // 0.125 * log2(e)
    const float C2 = 12.262908856239697f;     // 8.5  * log2(e)

    // partial output pointers for this half
    unsigned short* Oh = Op + (size_t)half * S_LEN * DOUT;
    float* Lh = Lp + (size_t)half * S_LEN * NKV * 4;

    // Q fragments (A-layout), loaded once
    short8v qf[2][2];
#pragma unroll
    for (int mf = 0; mf < 2; mf++)
#pragma unroll
        for (int ks = 0; ks < 2; ks++)
            qf[mf][ks] = *(const short8v*)(qb + (size_t)(s0 + mf * 16 + col) * QKVN +
                                           h * HD + ks * 32 + quad * 8);

    float4v O[2][4];
    float lsum[2][4];
#pragma unroll
    for (int mf = 0; mf < 2; mf++) {
#pragma unroll
        for (int df = 0; df < 4; df++) O[mf][df] = (float4v){0.f, 0.f, 0.f, 0.f};
#pragma unroll
        for (int r = 0; r < 4; r++) lsum[mf][r] = 0.f;
    }

    // staging addresses
    const int kkey = tid >> 2, kch = tid & 3;     // K: 4 threads/key, 16 shorts each
    const unsigned short* kg = kb + (size_t)kkey * QKVN + g * HD + kch * 16;
    const int vkey = tid & 63, vdb = tid >> 6;    // V: 1 thread/key, 16 dims
    const unsigned short* vg = vb + (size_t)vkey * QKVN + g * HD + vdb * 16;

    // preload first tile of this half into regs
    const size_t p0 = (size_t)it_lo * 64 * QKVN;
    ushort8v ka0 = *(const ushort8v*)(kg + p0);
    ushort8v ka1 = *(const ushort8v*)(kg + p0 + 8);
    ushort8v va0 = *(const ushort8v*)(vg + p0);
    ushort8v va1 = *(const ushort8v*)(vg + p0 + 8);

    for (int it = it_lo; it < it_hi; it++) {
        if (it > it_lo) __syncthreads();    // all reads of prev tile done
        // commit staged regs to LDS
        {
            unsigned short* kd = Ks + kkey * KSTR + kch * 16;
            *(ushort8v*)kd = ka0;
            *(ushort8v*)(kd + 8) = ka1;
            unsigned short* vd = Vt + (size_t)(vdb * 16) * KSTR + vkey;
#pragma unroll
            for (int j = 0; j < 8; j++) vd[j * KSTR] = va0[j];
#pragma unroll
            for (int j = 0; j < 8; j++) vd[(8 + j) * KSTR] = va1[j];
        }
        __syncthreads();
        // prefetch next tile into regs (latency hidden under full compute phase)
        if (it + 1 < it_hi) {
            const size_t off = (size_t)(it + 1) * 64 * QKVN;
            ka0 = *(const ushort8v*)(kg + off);
            ka1 = *(const ushort8v*)(kg + off + 8);
            va0 = *(const ushort8v*)(vg + off);
            va1 = *(const ushort8v*)(vg + off + 8);
        }

        const int t0 = it * 64;
        const bool edge = (t0 + 63 > s0);

        short8v kf[4][2];
#pragma unroll
        for (int nf = 0; nf < 4; nf++)
#pragma unroll
            for (int ks = 0; ks < 2; ks++)
                kf[nf][ks] = *(const short8v*)(Ks + (nf * 16 + col) * KSTR +
                                               ks * 32 + quad * 8);

#pragma unroll
        for (int mf = 0; mf < 2; mf++) {
            float4v sc[4];
#pragma unroll
            for (int nf = 0; nf < 4; nf++) {
                sc[nf] = (float4v){0.f, 0.f, 0.f, 0.f};
#pragma unroll
                for (int ks = 0; ks < 2; ks++)
                    sc[nf] = __builtin_amdgcn_mfma_f32_16x16x32_bf16(qf[mf][ks], kf[nf][ks],
                                                                     sc[nf], 0, 0, 0);
            }
            // fixed-max softmax: p = exp2(score*C1 - C2)
#pragma unroll
            for (int nf = 0; nf < 4; nf++)
#pragma unroll
                for (int r = 0; r < 4; r++) {
                    float arg = sc[nf][r] * C1 - C2;
                    if (edge) {
                        const int qg = s0 + mf * 16 + quad * 4 + r;
                        const int kg_ = t0 + nf * 16 + col;
                        arg = (kg_ <= qg) ? arg : -100.f;
                    }
                    const float p = exp2f(arg);
                    sc[nf][r] = p;
                    lsum[mf][r] += p;
                }
            // write P (bf16) to per-wave LDS tile, XOR-swizzled col-blocks
            unsigned short* pw = Ps + (size_t)(w * 32 + mf * 16 + quad * 4) * PPSTR;
#pragma unroll
            for (int nf = 0; nf < 4; nf++) {
                const int pb = (nf ^ quad) * 16;
#pragma unroll
                for (int r = 0; r < 4; r++)
                    pw[r * PPSTR + pb + col] = f2bf(sc[nf][r]);
            }
        }

        // PV: vf B-frags from Vt, pf A-frags from Ps (same-wave, no barrier)
        short8v vf[4][2];
#pragma unroll
        for (int df = 0; df < 4; df++)
#pragma unroll
            for (int ks = 0; ks < 2; ks++)
                vf[df][ks] = *(const short8v*)(Vt + (df * 16 + col) * KSTR +
                                               ks * 32 + quad * 8);
#pragma unroll
        for (int mf = 0; mf < 2; mf++)
#pragma unroll
            for (int ks = 0; ks < 2; ks++) {
                const int lb = ks * 2 + (quad >> 1);
                short8v pf = *(const short8v*)(Ps + (size_t)(w * 32 + mf * 16 + col) * PPSTR +
                                               ((lb ^ (col >> 2)) * 16 + (quad & 1) * 8));
#pragma unroll
                for (int df = 0; df < 4; df++)
                    O[mf][df] = __builtin_amdgcn_mfma_f32_16x16x32_bf16(pf, vf[df][ks],
                                                                        O[mf][df], 0, 0, 0);
            }
    }

    // epilogue: store partial l (reduced over the 16 cols) and partial O (fp16)
#pragma unroll
    for (int mf = 0; mf < 2; mf++)
#pragma unroll
        for (int r = 0; r < 4; r++) {
            float l = lsum[mf][r];
            l += __shfl_xor(l, 1); l += __shfl_xor(l, 2);
            l += __shfl_xor(l, 4); l += __shfl_xor(l, 8);
            if (col == 0)
                Lh[(size_t)(s0 + mf * 16 + quad * 4 + r) * NH + h] = l;
        }
#pragma unroll
    for (int mf = 0; mf < 2; mf++)
#pragma unroll
        for (int df = 0; df < 4; df++)
#pragma unroll
            for (int r = 0; r < 4; r++)
                Oh[(size_t)(s0 + mf * 16 + quad * 4 + r) * DOUT + h * HD + df * 16 + col] =
                    f2h(O[mf][df][r]);
}

// ---------------------------------------------------------------------------
// Combine: ctx = (O0 + O1) / (l0 + l1), bf16, written IN PLACE over O0.
// ---------------------------------------------------------------------------
__global__ __launch_bounds__(256) void combine(unsigned short* O01,   // no restrict: aliased out
                                               const float* __restrict__ Lp) {
    const int i4 = (blockIdx.x * 256 + threadIdx.x) * 4;
    const int s = i4 >> 11, h = (i4 & 2047) >> 6;
    const float inv = 1.0f / (Lp[(size_t)s * NH + h] +
                              Lp[(size_t)S_LEN * NH + (size_t)s * NH + h]);
    ushort4v o0 = *(const ushort4v*)(O01 + i4);
    ushort4v o1 = *(const ushort4v*)(O01 + (size_t)S_LEN * DOUT + i4);
    ushort4v r;
#pragma unroll
    for (int j = 0; j < 4; j++) r[j] = f2bf((h2f(o0[j]) + h2f(o1[j])) * inv);
    *(ushort4v*)(O01 + i4) = r;
}

// ---------------------------------------------------------------------------
extern "C" void kernel_launch(void* const* d_in, const int* in_sizes, int n_in,
                              void* d_out, int out_size, void* d_ws, size_t ws_size,
                              hipStream_t stream) {
    const float* x    = (const float*)d_in[0];
    const float* cosb = (const float*)d_in[2];
    const float* sinb = (const float*)d_in[3];
    const float* Wq   = (const float*)d_in[4];
    const float* Wk   = (const float*)d_in[5];
    const float* Wv   = (const float*)d_in[6];
    const float* Wo   = (const float*)d_in[7];
    const float* qw   = (const float*)d_in[8];
    const float* kw   = (const float*)d_in[9];
    float* out = (float*)d_out;

    // ws layout (41.9 MB):
    //   W1  [0, 12.58M)      qkv weights^T bf16   -- dead after gemm_qkv
    //   XB  [12.58, 20.97M)  x bf16               -- dead after gemm_qkv
    //   WoT [20.97, 29.36M)  Wo^T bf16
    //   QKV [29.36, 41.94M)  q|k|v bf16
    // flash partials OVERLAY the dead W1+XB region:
    //   O0 [0, 8.39M) fp16 ; O1 [8.39, 16.78M) fp16 ; L0,L1 [16.78, 17.30M) fp32
    // combine writes ctx bf16 in place over O0; out-proj reads it from there.
    unsigned short* W1  = (unsigned short*)d_ws;
    unsigned short* XB  = W1 + (size_t)QKVN * DIN;
    unsigned short* WoT = XB + (size_t)S_LEN * DIN;
    unsigned short* QKV = WoT + (size_t)DIN * DOUT;
    unsigned short* Op  = (unsigned short*)d_ws;
    float*          Lp  = (float*)(Op + (size_t)2 * S_LEN * DOUT);
    unsigned short* CTX = Op;

    dim3 blk256(256);

    prep<<<dim3(14336), blk256, 0, stream>>>(Wq, Wk, Wv, Wo, x, W1, WoT, XB);

    gemm64<1><<<dim3(QKVN / 64, S_LEN / 128), blk256, 0, stream>>>(
        XB, W1, QKV, S_LEN, QKVN, DIN, qw, kw, cosb, sinb);

    flash_part<<<dim3((S_LEN / 32) * NKV * 2), blk256, 0, stream>>>(
        QKV, QKV + KOFF, QKV + VOFF, Op, Lp);

    combine<<<dim3(S_LEN * DOUT / 1024), blk256, 0, stream>>>(Op, Lp);

    gemm64<0><<<dim3(DIN / 64, S_LEN / 128), blk256, 0, stream>>>(
        CTX, WoT, out, S_LEN, DIN, DOUT, nullptr, nullptr, nullptr, nullptr);
}